// Round 3
// baseline (407.916 us; speedup 1.0000x reference)
//
#include <hip/hip_runtime.h>

#define NN 100000
#define NE 1600000
#define D 64

// ---------------- Phase A: edge scatter  agg[row] += val * feat[col] --------
// One wave (64 lanes) per edge; lane = feature index. Gather is one coalesced
// 256B row read; scatter is 64 f32 atomics into agg[row].
__global__ __launch_bounds__(256) void scatter_k(const int* __restrict__ rows,
                                                 const int* __restrict__ cols,
                                                 const float* __restrict__ vals,
                                                 const float* __restrict__ feat,
                                                 float* __restrict__ agg) {
    int gtid = blockIdx.x * blockDim.x + threadIdx.x;
    int wave = gtid >> 6;
    int lane = threadIdx.x & 63;
    int nwaves = (gridDim.x * blockDim.x) >> 6;
    for (int e = wave; e < NE; e += nwaves) {
        int r = rows[e];
        int c = cols[e];
        float v = vals[e];
        float x = v * feat[(size_t)c * D + lane];
        atomicAdd(&agg[(size_t)r * D + lane], x);
    }
}

// ---------------- Phase B: out = leaky(agg@W1+b1) + leaky((agg*feat)@W2+b2) -
// Block = 256 threads = 4 waves, tile = 64 nodes.
// LDS: W1,W2 (32KB) + A,M tiles [64][65] (pad 65 -> bank=(lane+k)%32, 2-way free).
// Wave w computes d-slice [16w, 16w+16); lane owns node `lane` of the tile.
__global__ __launch_bounds__(256) void mlp_k(const float* __restrict__ agg,
                                             const float* __restrict__ feat,
                                             const float* __restrict__ W1,
                                             const float* __restrict__ b1,
                                             const float* __restrict__ W2,
                                             const float* __restrict__ b2,
                                             float* __restrict__ out) {
    __shared__ float W1s[64 * 64];
    __shared__ float W2s[64 * 64];
    __shared__ float b1s[64], b2s[64];
    __shared__ float As[64][65];
    __shared__ float Ms[64][65];

    for (int i = threadIdx.x; i < 4096; i += 256) {
        W1s[i] = W1[i];
        W2s[i] = W2[i];
    }
    if (threadIdx.x < 64) {
        b1s[threadIdx.x] = b1[threadIdx.x];
        b2s[threadIdx.x] = b2[threadIdx.x];
    }

    const int wv = threadIdx.x >> 6;
    const int lane = threadIdx.x & 63;
    const int ntiles = (NN + 63) / 64;

    for (int t = blockIdx.x; t < ntiles; t += gridDim.x) {
        const int base = t * 64;
        __syncthreads();  // covers weight staging (1st iter) + LDS reuse (later)
        // stage A (agg rows) and M (agg*feat rows), coalesced float4 loads
        for (int i = threadIdx.x; i < 64 * 16; i += 256) {
            int row = i >> 4;
            int c4 = (i & 15) << 2;
            int n = base + row;
            float4 a = make_float4(0.f, 0.f, 0.f, 0.f);
            float4 f = make_float4(0.f, 0.f, 0.f, 0.f);
            if (n < NN) {
                a = *reinterpret_cast<const float4*>(&agg[(size_t)n * D + c4]);
                f = *reinterpret_cast<const float4*>(&feat[(size_t)n * D + c4]);
            }
            As[row][c4 + 0] = a.x;
            As[row][c4 + 1] = a.y;
            As[row][c4 + 2] = a.z;
            As[row][c4 + 3] = a.w;
            Ms[row][c4 + 0] = a.x * f.x;
            Ms[row][c4 + 1] = a.y * f.y;
            Ms[row][c4 + 2] = a.z * f.z;
            Ms[row][c4 + 3] = a.w * f.w;
        }
        __syncthreads();

        const int dbase = wv * 16;
        float acc1[16], acc2[16];
#pragma unroll
        for (int j = 0; j < 16; ++j) {
            acc1[j] = b1s[dbase + j];
            acc2[j] = b2s[dbase + j];
        }
#pragma unroll 8
        for (int k = 0; k < 64; ++k) {
            float a = As[lane][k];
            float m = Ms[lane][k];
            const float4* w1p = reinterpret_cast<const float4*>(&W1s[k * 64 + dbase]);
            const float4* w2p = reinterpret_cast<const float4*>(&W2s[k * 64 + dbase]);
#pragma unroll
            for (int q = 0; q < 4; ++q) {
                float4 w1 = w1p[q];
                float4 w2 = w2p[q];
                acc1[q * 4 + 0] += a * w1.x;
                acc1[q * 4 + 1] += a * w1.y;
                acc1[q * 4 + 2] += a * w1.z;
                acc1[q * 4 + 3] += a * w1.w;
                acc2[q * 4 + 0] += m * w2.x;
                acc2[q * 4 + 1] += m * w2.y;
                acc2[q * 4 + 2] += m * w2.z;
                acc2[q * 4 + 3] += m * w2.w;
            }
        }

        const int n = base + lane;
        if (n < NN) {
#pragma unroll
            for (int q = 0; q < 4; ++q) {
                float r[4];
#pragma unroll
                for (int j = 0; j < 4; ++j) {
                    float x1 = acc1[q * 4 + j];
                    float x2 = acc2[q * 4 + j];
                    x1 = x1 >= 0.f ? x1 : 0.2f * x1;
                    x2 = x2 >= 0.f ? x2 : 0.2f * x2;
                    r[j] = x1 + x2;
                }
                *reinterpret_cast<float4*>(&out[(size_t)n * D + dbase + q * 4]) =
                    make_float4(r[0], r[1], r[2], r[3]);
            }
        }
    }
}

extern "C" void kernel_launch(void* const* d_in, const int* in_sizes, int n_in,
                              void* d_out, int out_size, void* d_ws, size_t ws_size,
                              hipStream_t stream) {
    const int* rows = (const int*)d_in[0];
    const int* cols = (const int*)d_in[1];
    const float* vals = (const float*)d_in[2];
    const float* feat = (const float*)d_in[3];
    const float* W1 = (const float*)d_in[4];
    const float* b1 = (const float*)d_in[5];
    const float* W2 = (const float*)d_in[6];
    const float* b2 = (const float*)d_in[7];
    float* out = (float*)d_out;
    float* agg = (float*)d_ws;  // N*64 f32 = 25.6 MB scratch

    hipMemsetAsync(agg, 0, (size_t)NN * D * sizeof(float), stream);
    scatter_k<<<2048, 256, 0, stream>>>(rows, cols, vals, feat, agg);

    const int ntiles = (NN + 63) / 64;
    mlp_k<<<ntiles, 256, 0, stream>>>(agg, feat, W1, b1, W2, b2, out);
}

// Round 9
// 292.223 us; speedup vs baseline: 1.3959x; 1.3959x over previous
//
#include <hip/hip_runtime.h>

#define NN 100000
#define NE 1600000
#define D 64
#define SCAN_BLK 1024
#define NSB ((NN + SCAN_BLK - 1) / SCAN_BLK)  // 98

static constexpr size_t OFF_AGG = 0;
static constexpr size_t OFF_RS  = 25600000;
static constexpr size_t OFF_CNT = 26000128;
static constexpr size_t OFF_BS  = 26400128;
static constexpr size_t OFF_ES  = 26400640;

// 1) histogram of rows
__global__ __launch_bounds__(256) void hist_k(const int* __restrict__ rows,
                                              int* __restrict__ cnt) {
    int stride = gridDim.x * blockDim.x;
    for (int e = blockIdx.x * blockDim.x + threadIdx.x; e < NE; e += stride)
        atomicAdd(&cnt[rows[e]], 1);
}

// 2a) per-1024-block exclusive scan; block sums out
__global__ __launch_bounds__(256) void scan1_k(const int* __restrict__ cnt,
                                               int* __restrict__ rs,
                                               int* __restrict__ bsum) {
    __shared__ int tsum[256];
    const int b = blockIdx.x;
    const int base = b * SCAN_BLK + threadIdx.x * 4;
    int v[4];
    int s = 0;
#pragma unroll
    for (int i = 0; i < 4; ++i) {
        int idx = base + i;
        v[i] = (idx < NN) ? cnt[idx] : 0;
        s += v[i];
    }
    tsum[threadIdx.x] = s;
    __syncthreads();
    int x = s;
    for (int off = 1; off < 256; off <<= 1) {
        int y = (threadIdx.x >= off) ? tsum[threadIdx.x - off] : 0;
        __syncthreads();
        x += y;
        tsum[threadIdx.x] = x;
        __syncthreads();
    }
    int run = x - s;
#pragma unroll
    for (int i = 0; i < 4; ++i) {
        int idx = base + i;
        if (idx < NN) rs[idx] = run;
        run += v[i];
    }
    if (threadIdx.x == 255) bsum[b] = x;
}

// 2b) exclusive scan of NSB block sums (parallel Hillis-Steele, 128 thr)
__global__ void scan2_k(int* __restrict__ bsum) {
    __shared__ int s[128];
    int i = threadIdx.x;
    int v = (i < NSB) ? bsum[i] : 0;
    s[i] = v;
    __syncthreads();
    int x = v;
    for (int off = 1; off < 128; off <<= 1) {
        int y = (i >= off) ? s[i - off] : 0;
        __syncthreads();
        x += y;
        s[i] = x;
        __syncthreads();
    }
    if (i < NSB) bsum[i] = x - v;  // exclusive
}

// 2c) add block offsets; cap entry
__global__ __launch_bounds__(256) void scan3_k(int* __restrict__ rs,
                                               const int* __restrict__ bsum) {
    int i = blockIdx.x * blockDim.x + threadIdx.x;
    if (i < NN) rs[i] += bsum[i >> 10];
    if (i == 0) rs[NN] = NE;
}

// 3) reorder edges into row-sorted packed (col, val) pairs — one 8B write
__global__ __launch_bounds__(256) void reorder_k(const int* __restrict__ rows,
                                                 const int* __restrict__ cols,
                                                 const float* __restrict__ vals,
                                                 const int* __restrict__ rs,
                                                 int* __restrict__ cur,
                                                 int2* __restrict__ edge_s) {
    int stride = gridDim.x * blockDim.x;
    for (int e = blockIdx.x * blockDim.x + threadIdx.x; e < NE; e += stride) {
        int r = rows[e];
        int p = rs[r] + atomicAdd(&cur[r], 1);
        edge_s[p] = make_int2(cols[e], __float_as_int(vals[e]));
    }
}

// 4) per-row gather-reduce, 4 edges in flight per wave.
//    lane = group g (lane>>4) x slot t (lane&15); group g handles edge 4*jj+g,
//    each lane loads float4 of the neighbor row (16 lanes x 16B = 256B).
//    Cross-group shfl_xor(16,32) reduce at the end; lanes 0-15 write the row.
__global__ __launch_bounds__(256) void gather_k(const int* __restrict__ rs,
                                                const int2* __restrict__ edge_s,
                                                const float* __restrict__ feat,
                                                float* __restrict__ agg) {
    const int lane = threadIdx.x & 63;
    const int g = lane >> 4;
    const int t = lane & 15;
    const int r = blockIdx.x * 4 + (threadIdx.x >> 6);
    if (r >= NN) return;
    const int s = rs[r], e = rs[r + 1];

    float4 acc = make_float4(0.f, 0.f, 0.f, 0.f);
    for (int base = s; base < e; base += 64) {
        int n = e - base;
        if (n > 64) n = 64;
        int c = 0;
        float v = 0.f;
        if (lane < n) {
            int2 ev = edge_s[base + lane];
            c = ev.x;
            v = __int_as_float(ev.y);
        }
        const int niter = (n + 3) >> 2;
        for (int jj = 0; jj < niter; ++jj) {
            int src = (jj << 2) + g;       // my group's edge slot
            int cj = __shfl(c, src);       // c=0 if src >= n (safe row 0)
            float vj = __shfl(v, src);     // v=0 if src >= n (no contribution)
            const float4 f =
                *reinterpret_cast<const float4*>(&feat[(size_t)cj * D + (t << 2)]);
            acc.x += vj * f.x;
            acc.y += vj * f.y;
            acc.z += vj * f.z;
            acc.w += vj * f.w;
        }
    }
    // sum the 4 groups (lanes t, t^16, t^32, t^48 hold partials of same feats)
    acc.x += __shfl_xor(acc.x, 16);
    acc.y += __shfl_xor(acc.y, 16);
    acc.z += __shfl_xor(acc.z, 16);
    acc.w += __shfl_xor(acc.w, 16);
    acc.x += __shfl_xor(acc.x, 32);
    acc.y += __shfl_xor(acc.y, 32);
    acc.z += __shfl_xor(acc.z, 32);
    acc.w += __shfl_xor(acc.w, 32);
    if (lane < 16)
        *reinterpret_cast<float4*>(&agg[(size_t)r * D + (t << 2)]) = acc;
}

// 5) out = leaky(agg@W1+b1) + leaky((agg*feat)@W2+b2)
__global__ __launch_bounds__(256) void mlp_k(const float* __restrict__ agg,
                                             const float* __restrict__ feat,
                                             const float* __restrict__ W1,
                                             const float* __restrict__ b1,
                                             const float* __restrict__ W2,
                                             const float* __restrict__ b2,
                                             float* __restrict__ out) {
    __shared__ float W1s[64 * 64];
    __shared__ float W2s[64 * 64];
    __shared__ float b1s[64], b2s[64];
    __shared__ float As[64][65];
    __shared__ float Ms[64][65];

    for (int i = threadIdx.x; i < 4096; i += 256) {
        W1s[i] = W1[i];
        W2s[i] = W2[i];
    }
    if (threadIdx.x < 64) {
        b1s[threadIdx.x] = b1[threadIdx.x];
        b2s[threadIdx.x] = b2[threadIdx.x];
    }

    const int wv = threadIdx.x >> 6;
    const int lane = threadIdx.x & 63;
    const int ntiles = (NN + 63) / 64;

    for (int t = blockIdx.x; t < ntiles; t += gridDim.x) {
        const int base = t * 64;
        __syncthreads();
        for (int i = threadIdx.x; i < 64 * 16; i += 256) {
            int row = i >> 4;
            int c4 = (i & 15) << 2;
            int n = base + row;
            float4 a = make_float4(0.f, 0.f, 0.f, 0.f);
            float4 f = make_float4(0.f, 0.f, 0.f, 0.f);
            if (n < NN) {
                a = *reinterpret_cast<const float4*>(&agg[(size_t)n * D + c4]);
                f = *reinterpret_cast<const float4*>(&feat[(size_t)n * D + c4]);
            }
            As[row][c4 + 0] = a.x;
            As[row][c4 + 1] = a.y;
            As[row][c4 + 2] = a.z;
            As[row][c4 + 3] = a.w;
            Ms[row][c4 + 0] = a.x * f.x;
            Ms[row][c4 + 1] = a.y * f.y;
            Ms[row][c4 + 2] = a.z * f.z;
            Ms[row][c4 + 3] = a.w * f.w;
        }
        __syncthreads();

        const int dbase = wv * 16;
        float acc1[16], acc2[16];
#pragma unroll
        for (int j = 0; j < 16; ++j) {
            acc1[j] = b1s[dbase + j];
            acc2[j] = b2s[dbase + j];
        }
#pragma unroll 8
        for (int k = 0; k < 64; ++k) {
            float a = As[lane][k];
            float m = Ms[lane][k];
            const float4* w1p = reinterpret_cast<const float4*>(&W1s[k * 64 + dbase]);
            const float4* w2p = reinterpret_cast<const float4*>(&W2s[k * 64 + dbase]);
#pragma unroll
            for (int q = 0; q < 4; ++q) {
                float4 w1 = w1p[q];
                float4 w2 = w2p[q];
                acc1[q * 4 + 0] += a * w1.x;
                acc1[q * 4 + 1] += a * w1.y;
                acc1[q * 4 + 2] += a * w1.z;
                acc1[q * 4 + 3] += a * w1.w;
                acc2[q * 4 + 0] += m * w2.x;
                acc2[q * 4 + 1] += m * w2.y;
                acc2[q * 4 + 2] += m * w2.z;
                acc2[q * 4 + 3] += m * w2.w;
            }
        }

        const int n = base + lane;
        if (n < NN) {
#pragma unroll
            for (int q = 0; q < 4; ++q) {
                float r[4];
#pragma unroll
                for (int j = 0; j < 4; ++j) {
                    float x1 = acc1[q * 4 + j];
                    float x2 = acc2[q * 4 + j];
                    x1 = x1 >= 0.f ? x1 : 0.2f * x1;
                    x2 = x2 >= 0.f ? x2 : 0.2f * x2;
                    r[j] = x1 + x2;
                }
                *reinterpret_cast<float4*>(&out[(size_t)n * D + dbase + q * 4]) =
                    make_float4(r[0], r[1], r[2], r[3]);
            }
        }
    }
}

extern "C" void kernel_launch(void* const* d_in, const int* in_sizes, int n_in,
                              void* d_out, int out_size, void* d_ws, size_t ws_size,
                              hipStream_t stream) {
    const int* rows = (const int*)d_in[0];
    const int* cols = (const int*)d_in[1];
    const float* vals = (const float*)d_in[2];
    const float* feat = (const float*)d_in[3];
    const float* W1 = (const float*)d_in[4];
    const float* b1 = (const float*)d_in[5];
    const float* W2 = (const float*)d_in[6];
    const float* b2 = (const float*)d_in[7];
    float* out = (float*)d_out;

    char* ws = (char*)d_ws;
    float* agg = (float*)(ws + OFF_AGG);
    int* rs = (int*)(ws + OFF_RS);
    int* cnt = (int*)(ws + OFF_CNT);
    int* bsum = (int*)(ws + OFF_BS);
    int2* edge_s = (int2*)(ws + OFF_ES);

    // CSR build: hist -> scan -> reorder
    hipMemsetAsync(cnt, 0, NN * sizeof(int), stream);
    hist_k<<<2048, 256, 0, stream>>>(rows, cnt);
    scan1_k<<<NSB, 256, 0, stream>>>(cnt, rs, bsum);
    hipMemsetAsync(cnt, 0, NN * sizeof(int), stream);  // reuse as cursor
    scan2_k<<<1, 128, 0, stream>>>(bsum);
    scan3_k<<<(NN + 255) / 256, 256, 0, stream>>>(rs, bsum);
    reorder_k<<<2048, 256, 0, stream>>>(rows, cols, vals, rs, cnt, edge_s);

    // per-row aggregation (no atomics, no agg memset needed)
    gather_k<<<(NN + 3) / 4, 256, 0, stream>>>(rs, edge_s, feat, agg);

    // MLP
    const int ntiles = (NN + 63) / 64;
    mlp_k<<<ntiles, 256, 0, stream>>>(agg, feat, W1, b1, W2, b2, out);
}